// Round 14
// baseline (467.957 us; speedup 1.0000x reference)
//
#include <hip/hip_runtime.h>
#include <stdint.h>

// Problem dims (fixed)
constexpr int T_DIM   = 16384;
constexpr int IN_DIM  = 4096;
constexpr int OUT_DIM = 4096;

using int32x4 = __attribute__((ext_vector_type(4))) int;

#define GLOAD_LDS16(g, l)                                                     \
    __builtin_amdgcn_global_load_lds(                                         \
        (const __attribute__((address_space(1))) void*)(uintptr_t)(g),        \
        (__attribute__((address_space(3))) void*)(uintptr_t)(l), 16, 0, 0)

// ===========================================================================
// Pre-pass A: int32 -> packed int8, pre-swizzled for BK=64 LDS path:
// within each 64-B group of 4 chunks, stored = chunk ^ ((row>>1)&3). (rule #21)
// ===========================================================================
__global__ void pack_a(const int* __restrict__ src, int8_t* __restrict__ dst,
                       int rows, int cols) {
    int64_t tid = (int64_t)blockIdx.x * blockDim.x + threadIdx.x;
    int64_t nchunks = (int64_t)rows * (cols / 16);
    if (tid >= nchunks) return;
    int row  = (int)(tid / (cols / 16));
    int cidx = (int)(tid % (cols / 16));
    const int32x4* s4 =
        reinterpret_cast<const int32x4*>(src + (int64_t)row * cols + (cidx << 4));
    uint32_t p[4];
#pragma unroll
    for (int v = 0; v < 4; ++v) {
        int32x4 t = s4[v];
        p[v] = (uint32_t)(t[0] & 0xff) | ((uint32_t)(t[1] & 0xff) << 8) |
               ((uint32_t)(t[2] & 0xff) << 16) | ((uint32_t)(t[3] & 0xff) << 24);
    }
    int cs = (cidx & ~3) | ((cidx & 3) ^ ((row >> 1) & 3));
    *reinterpret_cast<int32x4*>(dst + (int64_t)row * cols + (cs << 4)) =
        *reinterpret_cast<int32x4*>(p);
}

// ===========================================================================
// Pre-pass B: int32 -> packed int8 in MFMA-FRAGMENT-MAJOR order, so the GEMM
// loads B operands straight from global into the B-register fragment with
// one fully-coalesced global_load_dwordx4 per 16x64 block — NO LDS for B.
// Layout: 1KB block per (o_tile = o>>4, k_tile = k>>6);
//   byte offset in block = ((k>>4)&3)*256 + (o&15)*16 + (k&15)
//   (= lane*16 + byte for lane = g*16 + r, matching the i8 MFMA B-fragment:
//    lane (g,r) holds W[o_base + r][k: g*16 .. g*16+15])
// ===========================================================================
__global__ void pack_b(const int* __restrict__ src, int8_t* __restrict__ dst,
                       int rows, int cols) {
    int64_t tid = (int64_t)blockIdx.x * blockDim.x + threadIdx.x;
    int64_t nchunks = (int64_t)rows * (cols / 16);
    if (tid >= nchunks) return;
    int o  = (int)(tid / (cols / 16));
    int kc = (int)(tid % (cols / 16));   // 16-byte k-chunk index
    const int32x4* s4 =
        reinterpret_cast<const int32x4*>(src + (int64_t)o * cols + (kc << 4));
    uint32_t p[4];
#pragma unroll
    for (int v = 0; v < 4; ++v) {
        int32x4 t = s4[v];
        p[v] = (uint32_t)(t[0] & 0xff) | ((uint32_t)(t[1] & 0xff) << 8) |
               ((uint32_t)(t[2] & 0xff) << 16) | ((uint32_t)(t[3] & 0xff) << 24);
    }
    const int o_tile = o >> 4;
    const int k_tile = kc >> 2;          // k>>6
    const int g      = kc & 3;           // (k>>4)&3
    const int r      = o & 15;
    const int64_t off =
        ((int64_t)o_tile * (cols >> 6) + k_tile) * 1024 + g * 256 + r * 16;
    *reinterpret_cast<int32x4*>(dst + off) = *reinterpret_cast<int32x4*>(p);
}

// ===========================================================================
// Main GEMM — ROUND 11: B bypasses LDS.
// R3-R10 localized the wall: the CU's LDS port (reads + global_load_lds
// writes share it) demands ~1450cy/K-tile vs MFMA 1306cy — co-equal pipes,
// ~47% MfmaUtil ceiling for i8's double-rate MFMA (bf16 escapes because its
// MFMA cycles are 2x for the same LDS bytes). Occupancy (R10) and schedule
// (R3-R6) cannot fix a port-bandwidth tie; removing bytes can.
//   - B: fragment-major pack (above); per tile each wave does 4 coalesced
//     global_load_dwordx4 -> B regs directly. L2-resident (W' = 16MB).
//     Prefetched one tile ahead into b0/b1 (named swap, rule #20).
//   - A: unchanged proven LDS path (swizzled pack + global_load_lds + 8
//     ds_read_b128/wave). LDS port demand drops to ~880cy < MFMA 1306cy.
//   - 256x256 tile, BK=64, 8 waves (2Mx4N), per-wave 128x64, acc[8][4].
//   - LDS: 2 x 16KB A buffers only. Boundary: vmcnt(0)+barrier (drains
//     both next-tile A DMA and next-tile B regs ~2000cy after issue).
// ===========================================================================
constexpr int BM = 256, BN = 256, BK = 64;
constexpr int NT    = IN_DIM / BK;     // 64
constexpr int ATILE = BM * BK;         // 16 KiB
constexpr int NKT   = IN_DIM / 64;     // 64 k-tiles in B' layout

__global__ __launch_bounds__(512, 2)
void gemm_i8_bb(const int8_t* __restrict__ x8, const int8_t* __restrict__ w8p,
                const int* __restrict__ bias, const float* __restrict__ alphap,
                const float* __restrict__ betap, int* __restrict__ out) {
    __shared__ __align__(16) int8_t lds[2 * ATILE];   // 32 KiB (A only)

    const int tid  = threadIdx.x;
    const int lane = tid & 63;
    const int wid  = tid >> 6;
    const int wr   = wid >> 2;   // 0..1 (M)
    const int wc   = wid & 3;    // 0..3 (N)

    // XCD-chunked bijective swizzle (nwg = 1024, %8==0)
    const int nwg = gridDim.x;
    const int cpx = nwg >> 3;
    const int bid = blockIdx.x;
    const int swz = (bid & 7) * cpx + (bid >> 3);
    const int bm  = swz >> 4;    // 64 M-blocks
    const int bn  = swz & 15;    // 16 N-blocks
    const int brow = bm * BM;
    const int bcol = bn * BN;

    const float alpha = *alphap;
    const float beta  = *betap;

    const int g = lane >> 4;     // 16B k-chunk 0..3
    const int r = lane & 15;

    // ---- A staging: 2 moving global pointers (+BK/tile), 2 LDS dests.
    const int offA0 = tid * 16;           // rows 0..127
    const int offA1 = 8192 + tid * 16;    // rows 128..255
    const int8_t* pA0 = x8 + (int64_t)(brow + (offA0 >> 6)) * IN_DIM + (offA0 & 63);
    const int8_t* pA1 = x8 + (int64_t)(brow + (offA1 >> 6)) * IN_DIM + (offA1 & 63);
    const int dA0 = offA0, dA1 = offA1;

    // ---- B direct-load pointers: 4 per wave, advance +1024/tile.
    // o_tile for frag n = bcol/16 + wc*4 + n; block = (o_tile*NKT + t)*1024.
    const int8_t* pB[4];
#pragma unroll
    for (int n = 0; n < 4; ++n) {
        const int o_tile = (bcol >> 4) + wc * 4 + n;
        pB[n] = w8p + (int64_t)o_tile * NKT * 1024 + lane * 16;
    }

    // ---- A fragment byte-offsets (buffer-invariant; swizzle baked in)
    int aoff[8];
#pragma unroll
    for (int m = 0; m < 8; ++m) {
        const int row = wr * 128 + m * 16 + r;
        aoff[m] = row * BK + ((g ^ ((row >> 1) & 3)) << 4);
    }

    int32x4 acc[8][4] = {};
    int32x4 b0[4], b1[4];   // B fragment ping-pong (named, rule #20)

#define STAGE_A(DSTB)                                                         \
    do {                                                                      \
        int8_t* nb = lds + (DSTB) * ATILE;                                    \
        GLOAD_LDS16(pA0, nb + dA0);                                           \
        GLOAD_LDS16(pA1, nb + dA1);                                           \
        pA0 += BK; pA1 += BK;                                                 \
    } while (0)

#define LOAD_B(DST)                                                           \
    do {                                                                      \
        _Pragma("unroll") for (int n = 0; n < 4; ++n) {                       \
            DST[n] = *reinterpret_cast<const int32x4*>(pB[n]);                \
            pB[n] += 1024;                                                    \
        }                                                                     \
    } while (0)

    // Tile body: prefetch A(t+1) DMA + B(t+1) regs, ds_read A(t), 32 MFMA
    // on A(t) x BC(t), then vmcnt(0)+barrier boundary.
#define TILE(RB, SB, PF, BC, BNX, LAST)                                       \
    do {                                                                      \
        if (PF) { STAGE_A(SB); LOAD_B(BNX); }                                 \
        const int8_t* rb = lds + (RB) * ATILE;                                \
        int32x4 af[8];                                                        \
        _Pragma("unroll") for (int m = 0; m < 8; ++m)                         \
            af[m] = *reinterpret_cast<const int32x4*>(rb + aoff[m]);          \
        __builtin_amdgcn_s_setprio(1);                                        \
        _Pragma("unroll") for (int m = 0; m < 8; ++m)                         \
            _Pragma("unroll") for (int n = 0; n < 4; ++n)                     \
                acc[m][n] = __builtin_amdgcn_mfma_i32_16x16x64_i8(            \
                    af[m], BC[n], acc[m][n], 0, 0, 0);                        \
        __builtin_amdgcn_s_setprio(0);                                        \
        if (!(LAST)) {                                                        \
            asm volatile("s_waitcnt vmcnt(0)" ::: "memory");                  \
            __builtin_amdgcn_s_barrier();                                     \
            asm volatile("" ::: "memory");                                    \
        }                                                                     \
    } while (0)

    // Prologue: A(0) -> buf0, B(0) -> b0, drain, publish.
    STAGE_A(0);
    LOAD_B(b0);
    asm volatile("s_waitcnt vmcnt(0)" ::: "memory");
    __builtin_amdgcn_s_barrier();
    asm volatile("" ::: "memory");

    // Main loop: tiles 0..61 (31 iters x 2, literal indices; parity:
    // even t: BC=b0 fill b1, read buf0 stage buf1; odd t: swapped).
#pragma unroll 1
    for (int tt = 0; tt < NT - 2; tt += 2) {
        TILE(0, 1, true, b0, b1, false);
        TILE(1, 0, true, b1, b0, false);
    }
    TILE(0, 1, true,  b0, b1, false);   // t=62: stages A(63)->buf1, B(63)->b1
    TILE(1, 0, false, b1, b0, true);    // t=63: no prefetch, no boundary
#undef TILE
#undef LOAD_B
#undef STAGE_A

    // Epilogue: y = acc*alpha + bias*beta, round, clip, store int32.
    // C/D: col = lane&15, row = (lane>>4)*4 + j.
    const int r4 = (lane >> 4) * 4;
    const int cl = lane & 15;
#pragma unroll
    for (int n = 0; n < 4; ++n) {
        const int col = bcol + wc * 64 + n * 16 + cl;
        const float bterm = (float)bias[col] * beta;
#pragma unroll
        for (int m = 0; m < 8; ++m) {
            const int row0 = brow + wr * 128 + m * 16 + r4;
#pragma unroll
            for (int j = 0; j < 4; ++j) {
                float y = (float)acc[m][n][j] * alpha + bterm;
                y = rintf(y);
                y = fminf(fmaxf(y, -128.0f), 127.0f);
                out[(int64_t)(row0 + j) * OUT_DIM + col] = (int)y;
            }
        }
    }
}

// ===========================================================================
// Fallback (ws too small): reads int32 inputs directly, packs in regs,
// swizzled ds_write. 128x128 tile. Known-correct (round 2). Self-contained.
// ===========================================================================
__global__ __launch_bounds__(256)
void gemm_i8_fb(const int* __restrict__ x32, const int* __restrict__ w32,
                const int* __restrict__ bias, const float* __restrict__ alphap,
                const float* __restrict__ betap, int* __restrict__ out) {
    constexpr int FBM = 128, FBK = 128;
    __shared__ int8_t lA[FBM * FBK];
    __shared__ int8_t lB[FBM * FBK];

    const int tid  = threadIdx.x;
    const int wid  = tid >> 6;
    const int lane = tid & 63;
    const int nwg = gridDim.x;
    const int cpx = nwg >> 3;
    const int bid = blockIdx.x;
    const int swz = (bid & 7) * cpx + (bid >> 3);
    const int brow = (swz >> 5) * FBM;
    const int bcol = (swz & 31) * FBM;
    const int wr = wid >> 1, wc = wid & 1;
    const float alpha = *alphap;
    const float beta  = *betap;

    int32x4 acc[4][4] = {};
    for (int kt = 0; kt < IN_DIM / FBK; ++kt) {
        const int64_t kbase = (int64_t)kt * FBK;
#pragma unroll
        for (int q = 0; q < 4; ++q) {
            const int off = wid * 4096 + q * 1024 + lane * 16;
            const int row = off >> 7;
            const int k   = off & 127;
            const int* ga = x32 + (int64_t)(brow + row) * IN_DIM + kbase + k;
            const int* gb = w32 + (int64_t)(bcol + row) * IN_DIM + kbase + k;
            uint32_t pa[4], pb[4];
#pragma unroll
            for (int v = 0; v < 4; ++v) {
                int32x4 ta = reinterpret_cast<const int32x4*>(ga)[v];
                int32x4 tb = reinterpret_cast<const int32x4*>(gb)[v];
                pa[v] = (uint32_t)(ta[0] & 0xff) | ((uint32_t)(ta[1] & 0xff) << 8) |
                        ((uint32_t)(ta[2] & 0xff) << 16) | ((uint32_t)(ta[3] & 0xff) << 24);
                pb[v] = (uint32_t)(tb[0] & 0xff) | ((uint32_t)(tb[1] & 0xff) << 8) |
                        ((uint32_t)(tb[2] & 0xff) << 16) | ((uint32_t)(tb[3] & 0xff) << 24);
            }
            const int sc = ((k >> 4) ^ (row & 7)) << 4;
            *reinterpret_cast<int32x4*>(lA + row * FBK + sc) = *reinterpret_cast<int32x4*>(pa);
            *reinterpret_cast<int32x4*>(lB + row * FBK + sc) = *reinterpret_cast<int32x4*>(pb);
        }
        __syncthreads();
#pragma unroll
        for (int ks = 0; ks < 2; ++ks) {
            const int gg = lane >> 4, rr = lane & 15;
            const int lc = ks * 4 + gg;
            int32x4 af[4], bf[4];
#pragma unroll
            for (int m = 0; m < 4; ++m) {
                const int row = wr * 64 + m * 16 + rr;
                af[m] = *reinterpret_cast<const int32x4*>(lA + row * FBK + ((lc ^ (row & 7)) << 4));
            }
#pragma unroll
            for (int n = 0; n < 4; ++n) {
                const int row = wc * 64 + n * 16 + rr;
                bf[n] = *reinterpret_cast<const int32x4*>(lB + row * FBK + ((lc ^ (row & 7)) << 4));
            }
#pragma unroll
            for (int m = 0; m < 4; ++m)
#pragma unroll
                for (int n = 0; n < 4; ++n)
                    acc[m][n] = __builtin_amdgcn_mfma_i32_16x16x64_i8(af[m], bf[n], acc[m][n], 0, 0, 0);
        }
        __syncthreads();
    }
    const int r4 = (lane >> 4) * 4;
    const int cl = lane & 15;
#pragma unroll
    for (int n = 0; n < 4; ++n) {
        const int col = bcol + wc * 64 + n * 16 + cl;
        const float bterm = (float)bias[col] * beta;
#pragma unroll
        for (int m = 0; m < 4; ++m) {
            const int row0 = brow + wr * 64 + m * 16 + r4;
#pragma unroll
            for (int j = 0; j < 4; ++j) {
                float y = (float)acc[m][n][j] * alpha + bterm;
                y = rintf(y);
                y = fminf(fmaxf(y, -128.0f), 127.0f);
                out[(int64_t)(row0 + j) * OUT_DIM + col] = (int)y;
            }
        }
    }
}

// ===========================================================================
extern "C" void kernel_launch(void* const* d_in, const int* in_sizes, int n_in,
                              void* d_out, int out_size, void* d_ws, size_t ws_size,
                              hipStream_t stream) {
    const int*   x     = (const int*)d_in[0];
    const int*   w     = (const int*)d_in[1];
    const int*   bias  = (const int*)d_in[2];
    const float* alpha = (const float*)d_in[3];
    const float* beta  = (const float*)d_in[4];
    int*         out   = (int*)d_out;

    const size_t need = (size_t)T_DIM * IN_DIM + (size_t)OUT_DIM * IN_DIM;

    if (ws_size >= need) {
        int8_t* x8  = (int8_t*)d_ws;
        int8_t* w8p = x8 + (size_t)T_DIM * IN_DIM;
        {
            int64_t nch = (int64_t)T_DIM * (IN_DIM / 16);
            pack_a<<<(int)((nch + 255) / 256), 256, 0, stream>>>(x, x8, T_DIM, IN_DIM);
        }
        {
            int64_t nch = (int64_t)OUT_DIM * (IN_DIM / 16);
            pack_b<<<(int)((nch + 255) / 256), 256, 0, stream>>>(w, w8p, OUT_DIM, IN_DIM);
        }
        const int grid = (T_DIM / BM) * (OUT_DIM / BN);  // 64*16 = 1024
        gemm_i8_bb<<<grid, 512, 0, stream>>>(x8, w8p, bias, alpha, beta, out);
    } else {
        const int grid = (T_DIM / 128) * (OUT_DIM / 128);  // 4096
        gemm_i8_fb<<<grid, 256, 0, stream>>>(x, w, bias, alpha, beta, out);
    }
}

// Round 15
// 388.834 us; speedup vs baseline: 1.2035x; 1.2035x over previous
//
#include <hip/hip_runtime.h>
#include <stdint.h>

// Problem dims (fixed)
constexpr int T_DIM   = 16384;
constexpr int IN_DIM  = 4096;
constexpr int OUT_DIM = 4096;

using int32x4  = __attribute__((ext_vector_type(4)))  int;
using int32x16 = __attribute__((ext_vector_type(16))) int;

#define GLOAD_LDS16(g, l)                                                     \
    __builtin_amdgcn_global_load_lds(                                         \
        (const __attribute__((address_space(1))) void*)(uintptr_t)(g),        \
        (__attribute__((address_space(3))) void*)(uintptr_t)(l), 16, 0, 0)

// ===========================================================================
// Pre-pass: int32 (int8-valued) -> packed int8, pre-swizzled for BK=128:
// within each 128-B group of 8 chunks, stored = chunk ^ (row & 7). (rule #21)
// ===========================================================================
__global__ void pack_swz(const int* __restrict__ src, int8_t* __restrict__ dst,
                         int rows, int cols) {
    int64_t tid = (int64_t)blockIdx.x * blockDim.x + threadIdx.x;
    int64_t nchunks = (int64_t)rows * (cols / 16);
    if (tid >= nchunks) return;
    int row  = (int)(tid / (cols / 16));
    int cidx = (int)(tid % (cols / 16));
    const int32x4* s4 =
        reinterpret_cast<const int32x4*>(src + (int64_t)row * cols + (cidx << 4));
    uint32_t p[4];
#pragma unroll
    for (int v = 0; v < 4; ++v) {
        int32x4 t = s4[v];
        p[v] = (uint32_t)(t[0] & 0xff) | ((uint32_t)(t[1] & 0xff) << 8) |
               ((uint32_t)(t[2] & 0xff) << 16) | ((uint32_t)(t[3] & 0xff) << 24);
    }
    int cs = (cidx & ~7) | ((cidx & 7) ^ (row & 7));
    *reinterpret_cast<int32x4*>(dst + (int64_t)row * cols + (cs << 4)) =
        *reinterpret_cast<int32x4*>(p);
}

// ===========================================================================
// Main GEMM — ROUND 12: mfma_i32_32x32x32_i8 (4404 TOPS µbench vs 3944 for
// 16x16x64; -10% MFMA cycles, +12% ceiling) on the R9 structure (BK=128,
// 2 x 64KB LDS buffers, per-tile stage->other-buf + vmcnt(0)+barrier).
// Seven experiments established the serial-law wall: MFMA + LDS + DMA
// cycles add, schedule-independent. This cuts the MFMA addend.
//   A-frag (32x32x32): lane l holds A[row = l&31][k: (l>>5)*16 ..+16] ->
//     one b128/lane; addr = row*128 + ((khalf ^ (row&7))<<4), ks-step
//     address = base ^ (ks<<5) (chunk bits 1-2 are XOR-exact, no carry).
//   B-frag symmetric (col = l&31).
//   C/D (verified m74/m101, dtype-indep m121-128): col = lane&31,
//     row = (reg&3) + 8*(reg>>2) + 4*(lane>>5).
//   Per wave per tile: 24 ds_read_b128 (same as R9) + 32 MFMA @36.6cy.
//   acc = int32x16[4][2] = 128 AGPR; ~100 arch VGPR -> no spill.
// ===========================================================================
constexpr int BM = 256, BN = 256, BK = 128;
constexpr int NT    = IN_DIM / BK;     // 32
constexpr int ATILE = BM * BK;         // 32 KiB
constexpr int BUFSZ = 2 * ATILE;       // 64 KiB (A + B)

__global__ __launch_bounds__(512, 2)
void gemm_i8_32(const int8_t* __restrict__ x8, const int8_t* __restrict__ w8,
                const int* __restrict__ bias, const float* __restrict__ alphap,
                const float* __restrict__ betap, int* __restrict__ out) {
    __shared__ __align__(16) int8_t lds[2 * BUFSZ];   // 128 KiB

    const int tid  = threadIdx.x;
    const int lane = tid & 63;
    const int wid  = tid >> 6;
    const int wr   = wid >> 2;   // 0..1 (M)
    const int wc   = wid & 3;    // 0..3 (N)

    // XCD-chunked bijective swizzle (nwg = 1024, %8==0)
    const int nwg = gridDim.x;
    const int cpx = nwg >> 3;
    const int bid = blockIdx.x;
    const int swz = (bid & 7) * cpx + (bid >> 3);
    const int bm  = swz >> 4;    // 64 M-blocks
    const int bn  = swz & 15;    // 16 N-blocks
    const int brow = bm * BM;
    const int bcol = bn * BN;

    const float alpha = *alphap;
    const float beta  = *betap;

    const int lrow  = lane & 31;   // row/col within a 32-wide fragment
    const int khalf = lane >> 5;   // k half: 0 -> k 0..15, 1 -> k 16..31

    // ---- staging: 8 moving global pointers (+BK per tile), 8 LDS dests.
    const int8_t* pA[4];
    const int8_t* pB[4];
    int dA[4], dB[4];
#pragma unroll
    for (int l = 0; l < 4; ++l) {
        const int off = l * 8192 + tid * 16;
        const int row = off >> 7, in = off & 127;
        pA[l] = x8 + (int64_t)(brow + row) * IN_DIM + in;
        pB[l] = w8 + (int64_t)(bcol + row) * IN_DIM + in;
        dA[l] = off;
        dB[l] = ATILE + off;
    }

    // ---- fragment byte-offsets at ks=0 (ks-step: ^ (ks<<5)); swizzle baked
    int aoff[4], boff[2];
#pragma unroll
    for (int m = 0; m < 4; ++m) {
        const int row = wr * 128 + m * 32 + lrow;
        aoff[m] = row * BK + ((khalf ^ (row & 7)) << 4);
    }
#pragma unroll
    for (int n = 0; n < 2; ++n) {
        const int row = wc * 64 + n * 32 + lrow;
        boff[n] = ATILE + row * BK + ((khalf ^ (row & 7)) << 4);
    }

    int32x16 acc[4][2] = {};

#define STAGE8(DSTB)                                                          \
    do {                                                                      \
        int8_t* nb = lds + (DSTB) * BUFSZ;                                    \
        _Pragma("unroll") for (int l = 0; l < 4; ++l) {                       \
            GLOAD_LDS16(pA[l], nb + dA[l]);                                   \
            GLOAD_LDS16(pB[l], nb + dB[l]);                                   \
            pA[l] += BK; pB[l] += BK;                                         \
        }                                                                     \
    } while (0)

    // Tile body: stage t+1, 4 ks-steps of {6 reads + 8 MFMA}, boundary.
#define TILE(RB, SB, PF, LAST)                                                \
    do {                                                                      \
        const int8_t* rb = lds + (RB) * BUFSZ;                                \
        if (PF) STAGE8(SB);                                                   \
        _Pragma("unroll") for (int ks = 0; ks < 4; ++ks) {                    \
            int32x4 bf0 = *reinterpret_cast<const int32x4*>(                  \
                rb + (boff[0] ^ (ks << 5)));                                  \
            int32x4 bf1 = *reinterpret_cast<const int32x4*>(                  \
                rb + (boff[1] ^ (ks << 5)));                                  \
            int32x4 af[4];                                                    \
            _Pragma("unroll") for (int m = 0; m < 4; ++m)                     \
                af[m] = *reinterpret_cast<const int32x4*>(                    \
                    rb + (aoff[m] ^ (ks << 5)));                              \
            __builtin_amdgcn_s_setprio(1);                                    \
            _Pragma("unroll") for (int m = 0; m < 4; ++m) {                   \
                acc[m][0] = __builtin_amdgcn_mfma_i32_32x32x32_i8(            \
                    af[m], bf0, acc[m][0], 0, 0, 0);                          \
                acc[m][1] = __builtin_amdgcn_mfma_i32_32x32x32_i8(            \
                    af[m], bf1, acc[m][1], 0, 0, 0);                          \
            }                                                                 \
            __builtin_amdgcn_s_setprio(0);                                    \
        }                                                                     \
        if (!(LAST)) {                                                        \
            asm volatile("s_waitcnt vmcnt(0)" ::: "memory");                  \
            __builtin_amdgcn_s_barrier();                                     \
            asm volatile("" ::: "memory");                                    \
        }                                                                     \
    } while (0)

    // Prologue: stage tile 0 -> buf0, drain, publish.
    STAGE8(0);
    asm volatile("s_waitcnt vmcnt(0)" ::: "memory");
    __builtin_amdgcn_s_barrier();
    asm volatile("" ::: "memory");

    // Main loop: tiles 0..29 (15 iters x 2 tiles, literal buffer indices).
#pragma unroll 1
    for (int tt = 0; tt < NT - 2; tt += 2) {
        TILE(0, 1, true, false);
        TILE(1, 0, true, false);
    }
    TILE(0, 1, true,  false);   // t = 30, stages tile 31 -> buf1
    TILE(1, 0, false, true);    // t = 31, no stage, no boundary
#undef TILE
#undef STAGE8

    // Epilogue: y = acc*alpha + bias*beta, round, clip, store int32.
    // C/D 32x32: col = lane&31, row = (reg&3) + 8*(reg>>2) + 4*khalf.
#pragma unroll
    for (int n = 0; n < 2; ++n) {
        const int col = bcol + wc * 64 + n * 32 + lrow;
        const float bterm = (float)bias[col] * beta;
#pragma unroll
        for (int m = 0; m < 4; ++m) {
            const int rbase = brow + wr * 128 + m * 32 + khalf * 4;
#pragma unroll
            for (int q = 0; q < 4; ++q) {
#pragma unroll
                for (int j = 0; j < 4; ++j) {
                    float y = (float)acc[m][n][q * 4 + j] * alpha + bterm;
                    y = rintf(y);
                    y = fminf(fmaxf(y, -128.0f), 127.0f);
                    out[(int64_t)(rbase + q * 8 + j) * OUT_DIM + col] = (int)y;
                }
            }
        }
    }
}

// ===========================================================================
// Fallback (ws too small): reads int32 inputs directly, packs in regs,
// swizzled ds_write. 128x128 tile, 16x16x64 MFMA. Known-correct (round 2).
// ===========================================================================
__global__ __launch_bounds__(256)
void gemm_i8_fb(const int* __restrict__ x32, const int* __restrict__ w32,
                const int* __restrict__ bias, const float* __restrict__ alphap,
                const float* __restrict__ betap, int* __restrict__ out) {
    constexpr int FBM = 128, FBK = 128;
    __shared__ int8_t lA[FBM * FBK];
    __shared__ int8_t lB[FBM * FBK];

    const int tid  = threadIdx.x;
    const int wid  = tid >> 6;
    const int lane = tid & 63;
    const int nwg = gridDim.x;
    const int cpx = nwg >> 3;
    const int bid = blockIdx.x;
    const int swz = (bid & 7) * cpx + (bid >> 3);
    const int brow = (swz >> 5) * FBM;
    const int bcol = (swz & 31) * FBM;
    const int wr = wid >> 1, wc = wid & 1;
    const float alpha = *alphap;
    const float beta  = *betap;

    int32x4 acc[4][4] = {};
    for (int kt = 0; kt < IN_DIM / FBK; ++kt) {
        const int64_t kbase = (int64_t)kt * FBK;
#pragma unroll
        for (int q = 0; q < 4; ++q) {
            const int off = wid * 4096 + q * 1024 + lane * 16;
            const int row = off >> 7;
            const int k   = off & 127;
            const int* ga = x32 + (int64_t)(brow + row) * IN_DIM + kbase + k;
            const int* gb = w32 + (int64_t)(bcol + row) * IN_DIM + kbase + k;
            uint32_t pa[4], pb[4];
#pragma unroll
            for (int v = 0; v < 4; ++v) {
                int32x4 ta = reinterpret_cast<const int32x4*>(ga)[v];
                int32x4 tb = reinterpret_cast<const int32x4*>(gb)[v];
                pa[v] = (uint32_t)(ta[0] & 0xff) | ((uint32_t)(ta[1] & 0xff) << 8) |
                        ((uint32_t)(ta[2] & 0xff) << 16) | ((uint32_t)(ta[3] & 0xff) << 24);
                pb[v] = (uint32_t)(tb[0] & 0xff) | ((uint32_t)(tb[1] & 0xff) << 8) |
                        ((uint32_t)(tb[2] & 0xff) << 16) | ((uint32_t)(tb[3] & 0xff) << 24);
            }
            const int sc = ((k >> 4) ^ (row & 7)) << 4;
            *reinterpret_cast<int32x4*>(lA + row * FBK + sc) = *reinterpret_cast<int32x4*>(pa);
            *reinterpret_cast<int32x4*>(lB + row * FBK + sc) = *reinterpret_cast<int32x4*>(pb);
        }
        __syncthreads();
#pragma unroll
        for (int ks = 0; ks < 2; ++ks) {
            const int gg = lane >> 4, rr = lane & 15;
            const int lc = ks * 4 + gg;
            int32x4 af[4], bf[4];
#pragma unroll
            for (int m = 0; m < 4; ++m) {
                const int row = wr * 64 + m * 16 + rr;
                af[m] = *reinterpret_cast<const int32x4*>(lA + row * FBK + ((lc ^ (row & 7)) << 4));
            }
#pragma unroll
            for (int n = 0; n < 4; ++n) {
                const int row = wc * 64 + n * 16 + rr;
                bf[n] = *reinterpret_cast<const int32x4*>(lB + row * FBK + ((lc ^ (row & 7)) << 4));
            }
#pragma unroll
            for (int m = 0; m < 4; ++m)
#pragma unroll
                for (int n = 0; n < 4; ++n)
                    acc[m][n] = __builtin_amdgcn_mfma_i32_16x16x64_i8(af[m], bf[n], acc[m][n], 0, 0, 0);
        }
        __syncthreads();
    }
    const int r4 = (lane >> 4) * 4;
    const int cl = lane & 15;
#pragma unroll
    for (int n = 0; n < 4; ++n) {
        const int col = bcol + wc * 64 + n * 16 + cl;
        const float bterm = (float)bias[col] * beta;
#pragma unroll
        for (int m = 0; m < 4; ++m) {
            const int row0 = brow + wr * 64 + m * 16 + r4;
#pragma unroll
            for (int j = 0; j < 4; ++j) {
                float y = (float)acc[m][n][j] * alpha + bterm;
                y = rintf(y);
                y = fminf(fmaxf(y, -128.0f), 127.0f);
                out[(int64_t)(row0 + j) * OUT_DIM + col] = (int)y;
            }
        }
    }
}

// ===========================================================================
extern "C" void kernel_launch(void* const* d_in, const int* in_sizes, int n_in,
                              void* d_out, int out_size, void* d_ws, size_t ws_size,
                              hipStream_t stream) {
    const int*   x     = (const int*)d_in[0];
    const int*   w     = (const int*)d_in[1];
    const int*   bias  = (const int*)d_in[2];
    const float* alpha = (const float*)d_in[3];
    const float* beta  = (const float*)d_in[4];
    int*         out   = (int*)d_out;

    const size_t need = (size_t)T_DIM * IN_DIM + (size_t)OUT_DIM * IN_DIM;

    if (ws_size >= need) {
        int8_t* x8 = (int8_t*)d_ws;
        int8_t* w8 = x8 + (size_t)T_DIM * IN_DIM;
        {
            int64_t nch = (int64_t)T_DIM * (IN_DIM / 16);
            pack_swz<<<(int)((nch + 255) / 256), 256, 0, stream>>>(x, x8, T_DIM, IN_DIM);
        }
        {
            int64_t nch = (int64_t)OUT_DIM * (IN_DIM / 16);
            pack_swz<<<(int)((nch + 255) / 256), 256, 0, stream>>>(w, w8, OUT_DIM, IN_DIM);
        }
        const int grid = (T_DIM / BM) * (OUT_DIM / BN);  // 1024
        gemm_i8_32<<<grid, 512, 0, stream>>>(x8, w8, bias, alpha, beta, out);
    } else {
        const int grid = (T_DIM / 128) * (OUT_DIM / 128);  // 4096
        gemm_i8_fb<<<grid, 256, 0, stream>>>(x, w, bias, alpha, beta, out);
    }
}